// Round 6
// baseline (255.073 us; speedup 1.0000x reference)
//
#include <hip/hip_runtime.h>
#include <hip/hip_bf16.h>

typedef __bf16 bf16;
typedef __bf16 bf16x8 __attribute__((ext_vector_type(8)));
typedef __bf16 bf16x4 __attribute__((ext_vector_type(4)));
typedef float  f32x4  __attribute__((ext_vector_type(4)));

#define GLD_LDS(g, l)                                                        \
  __builtin_amdgcn_global_load_lds(                                          \
      (const __attribute__((address_space(1))) void*)(g),                    \
      (__attribute__((address_space(3))) void*)(l), 16, 0, 0)

#define SB()    __builtin_amdgcn_s_barrier()
#define LG0()   asm volatile("s_waitcnt lgkmcnt(0)" ::: "memory")
#define WVM(n)  asm volatile("s_waitcnt vmcnt(" #n ")" ::: "memory")
#define PRIO1() __builtin_amdgcn_s_setprio(1)
#define PRIO0() __builtin_amdgcn_s_setprio(0)

// ---------------------------------------------------------------------------
// 256x256, BK=64, 8 waves (2Mx4N), 8-phase QUADRANT-READ-AHEAD schedule.
// Phase p MFMAs a quadrant whose frags were read >=1 phase earlier; the
// 12-read next-tile q1 bucket is issued in ph4/ph8 (no-lgkm phases) so it
// drains under the MFMA burst. T even => tile T is always buf0, T+1 buf1.
//
// Reads:  pre/ph8: afA,bgA(buf0)[12] | ph1: bgB(buf0)[4] | ph2: afB(buf0)[8]
//         ph4: afA,bgA(buf1)[12]     | ph5: bgB(buf1)[4] | ph6: afB(buf1)[8]
// MFMAs:  ph1 q(0,0)b0 | ph2 q(0,1) | ph3 q(1,0) | ph4 q(1,1)
//         ph5 q(0,0)b1 | ph6 q(0,1) | ph7 q(1,0) | ph8 q(1,1)
// Stages: ph2 B(T+2)h0 | ph3 B(T+2)h1 | ph4 A(T+2)h0+h1
//         ph6 B(T+3)h0 | ph7 B(T+3)h1 + A(T+3)h0+h1
// Gates:  G1 end-ph3 vmcnt(4)  (T+1 complete; leaves ph2+ph3 stages)
//         G2 end-ph7 vmcnt(8)  (T+2 complete; leaves ph6+ph7 stages)
//         prologue: T0+T1 staged (16), vmcnt(8). Tail (s2 false): vmcnt(0).
// Overwrite-safety: every stage's LDS region had its readers drained by an
// LG0 >=1 phase before the stage issues (ph1/ph2/ph5/ph6 LG0s are the
// load-bearing ones); re-derived per region, both hazard directions.
// LDS 128K: A dbuf @0, B dbuf @65536; XOR swizzle (byte bits4-6 ^= row&7),
// write side pre-swizzles global k-chunk (rule #21 both-sides).
// C = A (MxK rm) * B^T (B NxK rm) + bias, fp32.  M,N %256==0, K%128==0.
// ---------------------------------------------------------------------------
__global__ __launch_bounds__(512, 2)
void gemm256(const bf16* __restrict__ A, const bf16* __restrict__ B,
             float* __restrict__ C, const float* __restrict__ bias_p,
             int M, int N, int K) {
  extern __shared__ bf16 lds[];
  const int tid  = threadIdx.x;
  const int lane = tid & 63, wave = tid >> 6;
  const int wm = wave >> 2, wn = wave & 3;       // 2 x 4 waves
  const int fr = lane & 15, fq = lane >> 4;
  const int xm = (fr & 7) << 4;
  const int kx0 = (fq * 16) ^ xm;
  const int kx1 = (fq * 16 + 64) ^ xm;

  // XCD-aware block swizzle (nwg divisible by 8)
  const int nwg = gridDim.x;
  const int bid = blockIdx.x;
  const int swz = (bid & 7) * (nwg >> 3) + (bid >> 3);
  const int gx  = N >> 8;
  const int row0 = (swz / gx) << 8, col0 = (swz % gx) << 8;

  // staging source (pre-swizzled k-chunk)
  const int srow = wave * 8 + (lane >> 3);
  const int scol = ((lane & 7) ^ (lane >> 3)) * 8;
  const bf16* Agl = A + (size_t)(row0 + srow) * K + scol;
  const bf16* Bgl = B + (size_t)(col0 + srow) * K + scol;

#define STG(gl, tb, t, h)                                                    \
  do {                                                                       \
    const size_t _k = (size_t)(t) * 64;                                      \
    GLD_LDS((gl) + (size_t)((h) * 128) * K + _k,                             \
            lds + (tb) + ((t) & 1) * 16384 + (h) * 8192 + wave * 512);       \
    GLD_LDS((gl) + (size_t)((h) * 128 + 64) * K + _k,                        \
            lds + (tb) + ((t) & 1) * 16384 + (h) * 8192 + 4096 + wave * 512);\
  } while (0)

  const char* ldsc = (const char*)lds;
  const char* Ab0 = ldsc + wm * 16384 + fr * 128 + kx0;
  const char* Ab1 = ldsc + wm * 16384 + fr * 128 + kx1;
  const char* Bb0 = ldsc + 65536 + wn * 8192 + fr * 128 + kx0;
  const char* Bb1 = ldsc + 65536 + wn * 8192 + fr * 128 + kx1;

  f32x4  acc[8][4] = {};
  bf16x8 afA[4][2], afB[4][2];   // mg=0 / mg=1 A-fragment sets
  bf16x8 bgA[2][2], bgB[2][2];   // np=0 / np=1 B-fragment sets

#define LDAF(AF, mgo, p)                                                     \
  do {                                                                       \
    _Pragma("unroll") for (int m_ = 0; m_ < 4; ++m_) {                       \
      AF[m_][0] = *(const bf16x8*)(Ab0 + (p) * 32768 + (mgo) + m_ * 2048);   \
      AF[m_][1] = *(const bf16x8*)(Ab1 + (p) * 32768 + (mgo) + m_ * 2048);   \
    }                                                                        \
  } while (0)

#define LDBF(BG, npo, p)                                                     \
  do {                                                                       \
    _Pragma("unroll") for (int n_ = 0; n_ < 2; ++n_) {                       \
      BG[n_][0] = *(const bf16x8*)(Bb0 + (p) * 32768 + (npo) + n_ * 2048);   \
      BG[n_][1] = *(const bf16x8*)(Bb1 + (p) * 32768 + (npo) + n_ * 2048);   \
    }                                                                        \
  } while (0)

#define MMX(AF, BG, mg, np)                                                  \
  do {                                                                       \
    _Pragma("unroll") for (int kk_ = 0; kk_ < 2; ++kk_)                      \
      _Pragma("unroll") for (int m_ = 0; m_ < 4; ++m_)                       \
        _Pragma("unroll") for (int n_ = 0; n_ < 2; ++n_)                     \
          acc[(mg) * 4 + m_][(np) * 2 + n_] =                                \
              __builtin_amdgcn_mfma_f32_16x16x32_bf16(                       \
                  AF[m_][kk_], BG[n_][kk_],                                  \
                  acc[(mg) * 4 + m_][(np) * 2 + n_], 0, 0, 0);               \
  } while (0)

  // prologue: stage T0 + T1 fully (16 loads); T0 guaranteed, T1 in flight
  STG(Agl, 0, 0, 0); STG(Agl, 0, 0, 1);
  STG(Bgl, 32768, 0, 0); STG(Bgl, 32768, 0, 1);
  STG(Agl, 0, 1, 0); STG(Agl, 0, 1, 1);
  STG(Bgl, 32768, 1, 0); STG(Bgl, 32768, 1, 1);
  WVM(8); SB();
  LDAF(afA, 0, 0); LDBF(bgA, 0, 0);   // q1 frags of T0

  const int NT = K >> 6;
  for (int T = 0; T < NT; T += 2) {
    const bool s2 = (T + 2 < NT);      // (NT even, T even => s3==s2)
    // ph1: MM q(0,0) buf0; read bgB(buf0)
    LDBF(bgB, 4096, 0);
    SB(); LG0(); PRIO1(); MMX(afA, bgA, 0, 0); PRIO0(); SB();
    // ph2: MM q(0,1); read afB(buf0); stage B(T+2)h0
    LDAF(afB, 8192, 0);
    if (s2) STG(Bgl, 32768, T + 2, 0);
    SB(); LG0(); PRIO1(); MMX(afA, bgB, 0, 1); PRIO0(); SB();
    // ph3: MM q(1,0); stage B(T+2)h1; gate G1
    if (s2) STG(Bgl, 32768, T + 2, 1);
    SB(); PRIO1(); MMX(afB, bgA, 1, 0); PRIO0();
    if (s2) { WVM(4); } else { WVM(0); }
    SB();
    // ph4: MM q(1,1); read afA,bgA(buf1) [drain under MFMA]; stage A(T+2)
    LDAF(afA, 0, 1); LDBF(bgA, 0, 1);
    if (s2) { STG(Agl, 0, T + 2, 0); STG(Agl, 0, T + 2, 1); }
    SB(); PRIO1(); MMX(afB, bgB, 1, 1); PRIO0(); SB();
    // ph5: MM q(0,0) buf1; read bgB(buf1)
    LDBF(bgB, 4096, 1);
    SB(); LG0(); PRIO1(); MMX(afA, bgA, 0, 0); PRIO0(); SB();
    // ph6: MM q(0,1); read afB(buf1); stage B(T+3)h0
    LDAF(afB, 8192, 1);
    if (s2) STG(Bgl, 32768, T + 3, 0);
    SB(); LG0(); PRIO1(); MMX(afA, bgB, 0, 1); PRIO0(); SB();
    // ph7: MM q(1,0); stage B(T+3)h1 + A(T+3); gate G2
    if (s2) { STG(Bgl, 32768, T + 3, 1); STG(Agl, 0, T + 3, 0); STG(Agl, 0, T + 3, 1); }
    SB(); PRIO1(); MMX(afB, bgA, 1, 0); PRIO0();
    if (s2) { WVM(8); } else { WVM(0); }
    SB();
    // ph8: MM q(1,1); read afA,bgA(buf0 = T+2) [drain under MFMA]
    if (s2) { LDAF(afA, 0, 0); LDBF(bgA, 0, 0); }
    SB(); PRIO1(); MMX(afB, bgB, 1, 1); PRIO0(); SB();
  }

  const float bias = bias_p[0];
#pragma unroll
  for (int m = 0; m < 8; ++m) {
#pragma unroll
    for (int n = 0; n < 4; ++n) {
      const int r = row0 + wm * 128 + m * 16 + fq * 4;
      const int c = col0 + wn * 64 + n * 16 + fr;
#pragma unroll
      for (int j = 0; j < 4; ++j)
        C[(size_t)(r + j) * N + c] = acc[m][n][j] + bias;
    }
  }
#undef STG
#undef LDAF
#undef LDBF
#undef MMX
}

// ---------------------------------------------------------------------------
// m97-structure 128x128 GEMM (small XW = X*W^T, bf16 out)
// ---------------------------------------------------------------------------
__global__ void gemm_bt(const bf16* __restrict__ A, const bf16* __restrict__ B,
                        bf16* __restrict__ Cb, int M, int N, int K) {
  __shared__ bf16 As[128 * 32];
  __shared__ bf16 Bs[128 * 32];
  const int tid  = threadIdx.x;
  const int lane = tid & 63;
  const int wave = tid >> 6;
  const int wr = wave >> 1, wc = wave & 1;
  const int fr = lane & 15, fq = lane >> 4;
  const int row0 = blockIdx.y * 128, col0 = blockIdx.x * 128;

  f32x4 acc[4][4] = {};
  const int c0 = tid, c1 = 256 + tid;
  const bf16* Ag0 = A + (size_t)(row0 + (c0 >> 2)) * K + (c0 & 3) * 8;
  const bf16* Ag1 = A + (size_t)(row0 + (c1 >> 2)) * K + (c1 & 3) * 8;
  const bf16* Bg0 = B + (size_t)(col0 + (c0 >> 2)) * K + (c0 & 3) * 8;
  const bf16* Bg1 = B + (size_t)(col0 + (c1 >> 2)) * K + (c1 & 3) * 8;
  bf16* Al0 = As + (wave * 64) * 8;
  bf16* Al1 = As + (256 + wave * 64) * 8;
  bf16* Bl0 = Bs + (wave * 64) * 8;
  bf16* Bl1 = Bs + (256 + wave * 64) * 8;

  for (int k0 = 0; k0 < K; k0 += 32) {
    GLD_LDS(Ag0 + k0, Al0);
    GLD_LDS(Ag1 + k0, Al1);
    GLD_LDS(Bg0 + k0, Bl0);
    GLD_LDS(Bg1 + k0, Bl1);
    __syncthreads();
    bf16x8 af[4], bgf[4];
#pragma unroll
    for (int m = 0; m < 4; ++m)
      af[m] = *(const bf16x8*)&As[(wr * 64 + m * 16 + fr) * 32 + fq * 8];
#pragma unroll
    for (int n = 0; n < 4; ++n)
      bgf[n] = *(const bf16x8*)&Bs[(wc * 64 + n * 16 + fr) * 32 + fq * 8];
#pragma unroll
    for (int m = 0; m < 4; ++m)
#pragma unroll
      for (int n = 0; n < 4; ++n)
        acc[m][n] = __builtin_amdgcn_mfma_f32_16x16x32_bf16(af[m], bgf[n],
                                                            acc[m][n], 0, 0, 0);
    __syncthreads();
  }
#pragma unroll
  for (int m = 0; m < 4; ++m)
#pragma unroll
    for (int n = 0; n < 4; ++n) {
      const int r  = row0 + wr * 64 + m * 16 + fq * 4;
      const int cc = col0 + wc * 64 + n * 16 + fr;
#pragma unroll
      for (int j = 0; j < 4; ++j)
        Cb[(size_t)(r + j) * N + cc] = (bf16)acc[m][n][j];
    }
}

__global__ void cvt_f32_bf16(const float* __restrict__ in, bf16* __restrict__ out,
                             int n4) {
  int i = blockIdx.x * blockDim.x + threadIdx.x;
  if (i >= n4) return;
  const float4 v = ((const float4*)in)[i];
  bf16x4 o;
  o[0] = (bf16)v.x; o[1] = (bf16)v.y; o[2] = (bf16)v.z; o[3] = (bf16)v.w;
  ((bf16x4*)out)[i] = o;
}

__global__ void transpose_cvt_w(const float* __restrict__ W, bf16* __restrict__ Wt) {
  __shared__ float s[32][33];
  const int tx = threadIdx.x & 31;
  const int ty = threadIdx.x >> 5;
  const int n0 = blockIdx.x * 32;
  const int k0 = blockIdx.y * 32;
#pragma unroll
  for (int p = 0; p < 4; ++p)
    s[ty + p * 8][tx] = W[(size_t)(k0 + ty + p * 8) * 1024 + n0 + tx];
  __syncthreads();
#pragma unroll
  for (int p = 0; p < 4; ++p)
    Wt[(size_t)(n0 + ty + p * 8) * 1024 + k0 + tx] = (bf16)s[tx][ty + p * 8];
}

extern "C" void kernel_launch(void* const* d_in, const int* in_sizes, int n_in,
                              void* d_out, int out_size, void* d_ws, size_t ws_size,
                              hipStream_t stream) {
  const float* X = (const float*)d_in[0];   // (8192, 1024)
  const float* W = (const float*)d_in[1];   // (1024, 1024)
  const float* b = (const float*)d_in[2];   // (1,)
  float* out = (float*)d_out;               // (8192, 8192)

  const int Nn = 8192, D = 1024;
  char* ws = (char*)d_ws;
  bf16* Xb  = (bf16*)(ws);
  bf16* XWb = (bf16*)(ws + (size_t)16 * 1024 * 1024);
  bf16* Wt  = (bf16*)(ws + (size_t)32 * 1024 * 1024);

  cvt_f32_bf16<<<(Nn * D / 4 + 255) / 256, 256, 0, stream>>>(X, Xb, Nn * D / 4);
  transpose_cvt_w<<<dim3(D / 32, D / 32), 256, 0, stream>>>(W, Wt);
  gemm_bt<<<dim3(D / 128, Nn / 128), 256, 0, stream>>>(Xb, Wt, XWb, Nn, D, D);
  gemm256<<<(Nn / 256) * (Nn / 256), 512, 131072, stream>>>(XWb, Xb, out, b,
                                                            Nn, Nn, D);
}

// Round 7
// 243.408 us; speedup vs baseline: 1.0479x; 1.0479x over previous
//
#include <hip/hip_runtime.h>
#include <hip/hip_bf16.h>

typedef __bf16 bf16;
typedef __bf16 bf16x8 __attribute__((ext_vector_type(8)));
typedef __bf16 bf16x4 __attribute__((ext_vector_type(4)));
typedef float  f32x4  __attribute__((ext_vector_type(4)));

#define GLD_LDS(g, l)                                                        \
  __builtin_amdgcn_global_load_lds(                                          \
      (const __attribute__((address_space(1))) void*)(g),                    \
      (__attribute__((address_space(3))) void*)(l), 16, 0, 0)

#define SB()    __builtin_amdgcn_s_barrier()
#define LG0()   asm volatile("s_waitcnt lgkmcnt(0)" ::: "memory")
#define WVM(n)  asm volatile("s_waitcnt vmcnt(" #n ")" ::: "memory")
#define PRIO1() __builtin_amdgcn_s_setprio(1)
#define PRIO0() __builtin_amdgcn_s_setprio(0)

// ---------------------------------------------------------------------------
// gemm128: 128x128 tile, BK=64, 4 waves (2Mx2N, wave tile 64x64), 8-phase
// R5-template schedule, LDS 64 KiB => 2 blocks/CU (independent barrier
// domains: cross-block overlap hides ds-drain, barrier skew, and epilogue).
// Per-thread staging ledger IDENTICAL to R5 (8 gld_lds/thread/K-tile, halves
// of 2): prologue T0(8)+T1.Ah0(2), WVM(2);
//   ph1 stage T+1.Ah1 | ph2 T+1.Bh0 | ph3 T+1.Bh1, gate WVM(2)@ph4
//   ph5 T+2.Ah1* | ph6 T+2.Bh0 | ph7 T+2.Bh1, ph4 T+2.Ah0, ph8 T+3.Ah0,
//   gate WVM(2)@ph8; tails WVM(0). Overwrite-safety: every stage's LDS
//   region had its readers drained by an LG0 >= 1 phase + barrier earlier
//   (ph2/ph3/ph7 LG0s are load-bearing) — verified per region.
// LDS: A dbuf 2x16KB @0, B dbuf 2x16KB @32768. XOR swizzle: byte bits 4-6
//   ^= row&7 on reads; write side pre-swizzles the global k-chunk
//   (col16 = (lane&7)^(lane>>3), linear gld_lds dest) — rule #21 both-sides.
// C = A (MxK rm) * B^T (B NxK rm) + bias, fp32. M,N %128==0, K%128==0.
// ---------------------------------------------------------------------------
__global__ __launch_bounds__(256, 2)
void gemm128(const bf16* __restrict__ A, const bf16* __restrict__ B,
             float* __restrict__ C, const float* __restrict__ bias_p,
             int M, int N, int K) {
  extern __shared__ bf16 lds[];
  const int tid  = threadIdx.x;
  const int lane = tid & 63, wave = tid >> 6;      // 4 waves
  const int wm = wave >> 1, wn = wave & 1;         // 2 x 2
  const int fr = lane & 15, fq = lane >> 4;
  const int xm = (fr & 7) << 4;
  const int kx0 = (fq * 16) ^ xm;
  const int kx1 = (fq * 16 + 64) ^ xm;

  // XCD-aware block swizzle (nwg divisible by 8)
  const int nwg = gridDim.x;
  const int bid = blockIdx.x;
  const int swz = (bid & 7) * (nwg >> 3) + (bid >> 3);
  const int gx  = N >> 7;
  const int row0 = (swz / gx) << 7, col0 = (swz % gx) << 7;

  // staging source (pre-swizzled k-chunk). Each gld_lds issue: 256 thr x 16B
  // = 4 KB = 32 rows x 128 B; srow = wave*8 + lane/8 in [0,32).
  const int srow = wave * 8 + (lane >> 3);
  const int scol = ((lane & 7) ^ (lane >> 3)) * 8;
  const bf16* Agl = A + (size_t)(row0 + srow) * K + scol;
  const bf16* Bgl = B + (size_t)(col0 + srow) * K + scol;

  // stage half h (64 rows = 2 issues) of K-tile t; tb elems: A=0, B=16384
#define STG(gl, tb, t, h)                                                    \
  do {                                                                       \
    const size_t _k = (size_t)(t) * 64;                                      \
    GLD_LDS((gl) + (size_t)((h) * 64) * K + _k,                              \
            lds + (tb) + ((t) & 1) * 8192 + (h) * 4096 + wave * 512);        \
    GLD_LDS((gl) + (size_t)((h) * 64 + 32) * K + _k,                         \
            lds + (tb) + ((t) & 1) * 8192 + (h) * 4096 + 2048 + wave * 512); \
  } while (0)

  const char* ldsc = (const char*)lds;
  const char* Ab0 = ldsc + wm * 8192 + fr * 128 + kx0;
  const char* Ab1 = ldsc + wm * 8192 + fr * 128 + kx1;
  const char* Bb0 = ldsc + 32768 + wn * 8192 + fr * 128 + kx0;
  const char* Bb1 = ldsc + 32768 + wn * 8192 + fr * 128 + kx1;

  f32x4  acc[4][4] = {};
  bf16x8 af[2][2];   // current mg half (2 m-frags x 2 kk)
  bf16x8 bg[4][2];   // ALL 4 n-frags for the K-tile (held across phases)

#define LDA(mg, p)                                                           \
  do {                                                                       \
    _Pragma("unroll") for (int m_ = 0; m_ < 2; ++m_) {                       \
      af[m_][0] = *(const bf16x8*)(Ab0 + (p) * 16384 + (mg) * 4096 + m_ * 2048);\
      af[m_][1] = *(const bf16x8*)(Ab1 + (p) * 16384 + (mg) * 4096 + m_ * 2048);\
    }                                                                        \
  } while (0)

#define LDB(np, p)                                                           \
  do {                                                                       \
    _Pragma("unroll") for (int n_ = 0; n_ < 2; ++n_) {                       \
      bg[(np) * 2 + n_][0] =                                                 \
          *(const bf16x8*)(Bb0 + (p) * 16384 + (np) * 4096 + n_ * 2048);     \
      bg[(np) * 2 + n_][1] =                                                 \
          *(const bf16x8*)(Bb1 + (p) * 16384 + (np) * 4096 + n_ * 2048);     \
    }                                                                        \
  } while (0)

#define MM(mg, np)                                                           \
  do {                                                                       \
    _Pragma("unroll") for (int kk_ = 0; kk_ < 2; ++kk_)                      \
      _Pragma("unroll") for (int m_ = 0; m_ < 2; ++m_)                       \
        _Pragma("unroll") for (int n_ = 0; n_ < 2; ++n_)                     \
          acc[(mg) * 2 + m_][(np) * 2 + n_] =                                \
              __builtin_amdgcn_mfma_f32_16x16x32_bf16(                       \
                  af[m_][kk_], bg[(np) * 2 + n_][kk_],                       \
                  acc[(mg) * 2 + m_][(np) * 2 + n_], 0, 0, 0);               \
  } while (0)

  // prologue: T0 (4 halves = 8 loads) + T1.Ah0 (2); keep newest 2 in flight
  STG(Agl, 0, 0, 0); STG(Agl, 0, 0, 1);
  STG(Bgl, 16384, 0, 0); STG(Bgl, 16384, 0, 1);
  STG(Agl, 0, 1, 0);
  WVM(2); SB();

  const int NT = K >> 6;
  for (int T = 0; T < NT; T += 2) {
    const bool s2 = (T + 2 < NT), s3 = (T + 3 < NT);
    // ph1
    LDA(0, 0); LDB(0, 0);
    STG(Agl, 0, T + 1, 1);
    SB(); LG0(); PRIO1(); MM(0, 0); PRIO0(); SB();
    // ph2
    LDB(1, 0);
    STG(Bgl, 16384, T + 1, 0);
    SB(); LG0(); PRIO1(); MM(0, 1); PRIO0(); SB();
    // ph3
    LDA(1, 0);
    STG(Bgl, 16384, T + 1, 1);
    SB(); LG0(); PRIO1(); MM(1, 0); PRIO0(); SB();
    // ph4 (no reads)
    if (s2) STG(Agl, 0, T + 2, 0);
    SB(); PRIO1(); MM(1, 1); PRIO0();
    if (s2) { WVM(2); } else { WVM(0); }
    SB();
    // ph5
    LDA(0, 1); LDB(0, 1);
    if (s2) STG(Agl, 0, T + 2, 1);
    SB(); LG0(); PRIO1(); MM(0, 0); PRIO0(); SB();
    // ph6
    LDB(1, 1);
    if (s2) STG(Bgl, 16384, T + 2, 0);
    SB(); LG0(); PRIO1(); MM(0, 1); PRIO0(); SB();
    // ph7
    LDA(1, 1);
    if (s2) STG(Bgl, 16384, T + 2, 1);
    SB(); LG0(); PRIO1(); MM(1, 0); PRIO0(); SB();
    // ph8 (no reads)
    if (s3) STG(Agl, 0, T + 3, 0);
    SB(); PRIO1(); MM(1, 1); PRIO0();
    if (s3) { WVM(2); } else { WVM(0); }
    SB();
  }

  const float bias = bias_p[0];
#pragma unroll
  for (int m = 0; m < 4; ++m) {
#pragma unroll
    for (int n = 0; n < 4; ++n) {
      const int r = row0 + wm * 64 + m * 16 + fq * 4;
      const int c = col0 + wn * 64 + n * 16 + fr;
#pragma unroll
      for (int j = 0; j < 4; ++j)
        C[(size_t)(r + j) * N + c] = acc[m][n][j] + bias;
    }
  }
#undef STG
#undef LDA
#undef LDB
#undef MM
}

// ---------------------------------------------------------------------------
// m97-structure 128x128 GEMM (small XW = X*W^T, bf16 out)
// ---------------------------------------------------------------------------
__global__ void gemm_bt(const bf16* __restrict__ A, const bf16* __restrict__ B,
                        bf16* __restrict__ Cb, int M, int N, int K) {
  __shared__ bf16 As[128 * 32];
  __shared__ bf16 Bs[128 * 32];
  const int tid  = threadIdx.x;
  const int lane = tid & 63;
  const int wave = tid >> 6;
  const int wr = wave >> 1, wc = wave & 1;
  const int fr = lane & 15, fq = lane >> 4;
  const int row0 = blockIdx.y * 128, col0 = blockIdx.x * 128;

  f32x4 acc[4][4] = {};
  const int c0 = tid, c1 = 256 + tid;
  const bf16* Ag0 = A + (size_t)(row0 + (c0 >> 2)) * K + (c0 & 3) * 8;
  const bf16* Ag1 = A + (size_t)(row0 + (c1 >> 2)) * K + (c1 & 3) * 8;
  const bf16* Bg0 = B + (size_t)(col0 + (c0 >> 2)) * K + (c0 & 3) * 8;
  const bf16* Bg1 = B + (size_t)(col0 + (c1 >> 2)) * K + (c1 & 3) * 8;
  bf16* Al0 = As + (wave * 64) * 8;
  bf16* Al1 = As + (256 + wave * 64) * 8;
  bf16* Bl0 = Bs + (wave * 64) * 8;
  bf16* Bl1 = Bs + (256 + wave * 64) * 8;

  for (int k0 = 0; k0 < K; k0 += 32) {
    GLD_LDS(Ag0 + k0, Al0);
    GLD_LDS(Ag1 + k0, Al1);
    GLD_LDS(Bg0 + k0, Bl0);
    GLD_LDS(Bg1 + k0, Bl1);
    __syncthreads();
    bf16x8 af[4], bgf[4];
#pragma unroll
    for (int m = 0; m < 4; ++m)
      af[m] = *(const bf16x8*)&As[(wr * 64 + m * 16 + fr) * 32 + fq * 8];
#pragma unroll
    for (int n = 0; n < 4; ++n)
      bgf[n] = *(const bf16x8*)&Bs[(wc * 64 + n * 16 + fr) * 32 + fq * 8];
#pragma unroll
    for (int m = 0; m < 4; ++m)
#pragma unroll
      for (int n = 0; n < 4; ++n)
        acc[m][n] = __builtin_amdgcn_mfma_f32_16x16x32_bf16(af[m], bgf[n],
                                                            acc[m][n], 0, 0, 0);
    __syncthreads();
  }
#pragma unroll
  for (int m = 0; m < 4; ++m)
#pragma unroll
    for (int n = 0; n < 4; ++n) {
      const int r  = row0 + wr * 64 + m * 16 + fq * 4;
      const int cc = col0 + wc * 64 + n * 16 + fr;
#pragma unroll
      for (int j = 0; j < 4; ++j)
        Cb[(size_t)(r + j) * N + cc] = (bf16)acc[m][n][j];
    }
}

__global__ void cvt_f32_bf16(const float* __restrict__ in, bf16* __restrict__ out,
                             int n4) {
  int i = blockIdx.x * blockDim.x + threadIdx.x;
  if (i >= n4) return;
  const float4 v = ((const float4*)in)[i];
  bf16x4 o;
  o[0] = (bf16)v.x; o[1] = (bf16)v.y; o[2] = (bf16)v.z; o[3] = (bf16)v.w;
  ((bf16x4*)out)[i] = o;
}

__global__ void transpose_cvt_w(const float* __restrict__ W, bf16* __restrict__ Wt) {
  __shared__ float s[32][33];
  const int tx = threadIdx.x & 31;
  const int ty = threadIdx.x >> 5;
  const int n0 = blockIdx.x * 32;
  const int k0 = blockIdx.y * 32;
#pragma unroll
  for (int p = 0; p < 4; ++p)
    s[ty + p * 8][tx] = W[(size_t)(k0 + ty + p * 8) * 1024 + n0 + tx];
  __syncthreads();
#pragma unroll
  for (int p = 0; p < 4; ++p)
    Wt[(size_t)(n0 + ty + p * 8) * 1024 + k0 + tx] = (bf16)s[tx][ty + p * 8];
}

extern "C" void kernel_launch(void* const* d_in, const int* in_sizes, int n_in,
                              void* d_out, int out_size, void* d_ws, size_t ws_size,
                              hipStream_t stream) {
  const float* X = (const float*)d_in[0];   // (8192, 1024)
  const float* W = (const float*)d_in[1];   // (1024, 1024)
  const float* b = (const float*)d_in[2];   // (1,)
  float* out = (float*)d_out;               // (8192, 8192)

  const int Nn = 8192, D = 1024;
  char* ws = (char*)d_ws;
  bf16* Xb  = (bf16*)(ws);
  bf16* XWb = (bf16*)(ws + (size_t)16 * 1024 * 1024);
  bf16* Wt  = (bf16*)(ws + (size_t)32 * 1024 * 1024);

  cvt_f32_bf16<<<(Nn * D / 4 + 255) / 256, 256, 0, stream>>>(X, Xb, Nn * D / 4);
  transpose_cvt_w<<<dim3(D / 32, D / 32), 256, 0, stream>>>(W, Wt);
  gemm_bt<<<dim3(D / 128, Nn / 128), 256, 0, stream>>>(Xb, Wt, XWb, Nn, D, D);
  gemm128<<<(Nn / 128) * (Nn / 128), 256, 65536, stream>>>(XWb, Xb, out, b,
                                                           Nn, Nn, D);
}

// Round 8
// 204.536 us; speedup vs baseline: 1.2471x; 1.1901x over previous
//
#include <hip/hip_runtime.h>
#include <hip/hip_bf16.h>

typedef __bf16 bf16;
typedef __bf16 bf16x8 __attribute__((ext_vector_type(8)));
typedef __bf16 bf16x4 __attribute__((ext_vector_type(4)));
typedef float  f32x4  __attribute__((ext_vector_type(4)));

#define GLD_LDS(g, l)                                                        \
  __builtin_amdgcn_global_load_lds(                                          \
      (const __attribute__((address_space(1))) void*)(g),                    \
      (__attribute__((address_space(3))) void*)(l), 16, 0, 0)

#define SB()    __builtin_amdgcn_s_barrier()
#define WVM(n)  asm volatile("s_waitcnt vmcnt(" #n ")" ::: "memory")
#define PRIO1() __builtin_amdgcn_s_setprio(1)
#define PRIO0() __builtin_amdgcn_s_setprio(0)

// ---------------------------------------------------------------------------
// gemm256 v3: 256x256 tile, BK=32, QUAD-buffered LDS (128 KiB), 8 waves
// (2Mx4N, wave tile 128x64), 2 phases per K-tile, REGISTER READ-AHEAD:
//   ph1(T): [stage ALL of tile T+3 (4 gld_lds)] [read afB = A.mg1(T), 4]
//           [MFMA mg0(T) w/ afA,bg read last phase] [SB]
//   ph2(T): [read afA = A.mg0(T+1), bg' = B(T+1), 8]  (T+1 resident: gated
//           at end-(T-1))  [MFMA mg1(T)] [gate: vmcnt(4) if T+3<NT else 0] [SB]
// NO hand lgkmcnt: compiler emits partial lgkm waits for MFMA deps, so this
// phase's reads drain UNDER the MFMA burst (in-wave overlap).
// Ledger (stage-3-ahead, tile S staged during S-3.ph1, buf S&3):
//   - buf reuse: buf[S&3] last read at (S-4).ph1 (afB); its consuming MFMA
//     is (S-4).ph2 => read retired 2 phases + barriers before stage issues.
//   - residency: gate at end-(S-2) = WVM(4) leaves only (S-2).ph1's 4 loads
//     (-> S+1); drains (S-3).ph1's (-> S). First read of S is (S-1).ph2,
//     after that gate's SB => cross-wave safe. Slack ~2 phases.
//   - reads can't hoist past the protecting gate: WVM has a memory clobber.
//   - tail: stages skipped when S>=NT; gate WVM(0) when T+3>=NT.
// LDS: A 4x16KB @0, B 4x16KB @65536 (byte offsets; imm-offset ds_reads).
// Paired-row swizzled layout per tile [128 lines x 128B], line l holds rows
// 2l,2l+1 (64B each, as 8 granules of 16B):  granule g of line l holds
// (row 2l + h, kchunk fq) with h*4+fq = g ^ (l&7).  Conflict-free b128 reads
// (each 8-lane group hits all 8 granule slots - XOR coset) and linear
// gld_lds dest with pre-swizzled per-thread global source (rule #21).
// C = A (MxK rm) * B^T (B NxK rm) + bias, fp32. M,N%256==0, K%128==0.
// ---------------------------------------------------------------------------
__global__ __launch_bounds__(512, 2)
void gemm256(const bf16* __restrict__ A, const bf16* __restrict__ B,
             float* __restrict__ C, const float* __restrict__ bias_p,
             int M, int N, int K) {
  extern __shared__ bf16 lds[];
  const int tid  = threadIdx.x;
  const int lane = tid & 63, wave = tid >> 6;
  const int wm = wave >> 2, wn = wave & 3;       // 2 x 4 waves
  const int fr = lane & 15, fq = lane >> 4;

  // XCD-aware block swizzle (nwg divisible by 8)
  const int nwg = gridDim.x;
  const int bid = blockIdx.x;
  const int swz = (bid & 7) * (nwg >> 3) + (bid >> 3);
  const int gx  = N >> 8;
  const int row0 = (swz / gx) << 8, col0 = (swz % gx) << 8;

  // ---- staging source (pre-swizzled: thread t writes LDS linear t*16B) ----
  const int gsw_t = (tid & 7) ^ ((tid >> 3) & 7);
  const int ht    = gsw_t >> 2;          // row parity bit
  const int fqt   = gsw_t & 3;           // k-chunk
  const int srow  = 2 * (tid >> 3) + ht; // row within 128-row half
  const bf16* Asrc = A + (size_t)(row0 + srow) * K + fqt * 8;
  const bf16* Bsrc = B + (size_t)(col0 + srow) * K + fqt * 8;

  // stage ALL of K-tile t (A h0,h1 + B h0,h1 = 4 gld_lds); buf = t&3
#define STG_ALL(t)                                                           \
  do {                                                                       \
    const int _b = ((t) & 3) * 8192;       /* elems */                       \
    const size_t _k = (size_t)(t) * 32;                                      \
    GLD_LDS(Asrc + _k,                   lds + _b + wave * 512);             \
    GLD_LDS(Asrc + (size_t)128 * K + _k, lds + _b + 4096 + wave * 512);      \
    GLD_LDS(Bsrc + _k,                   lds + 32768 + _b + wave * 512);     \
    GLD_LDS(Bsrc + (size_t)128 * K + _k, lds + 32768 + _b + 4096 + wave * 512);\
  } while (0)

  // ---- LDS read bases (lane-constant swizzle term) ----
  const int gsw_r = ((fr & 1) * 4 + fq) ^ (fr >> 1);
  const int laneb = (fr >> 1) * 128 + gsw_r * 16;
  const char* ldsc  = (const char*)lds;
  const char* Abase = ldsc + wm * 8192 + laneb;          // + buf*16K + mg*4K + m*1K
  const char* Bbase = ldsc + 65536 + wn * 4096 + laneb;  // + buf*16K + n*1K

  f32x4  acc[8][4] = {};
  bf16x8 afA[4], afB[4];     // A mg0 / mg1 fragment sets (current/next tile)
  bf16x8 bgE[4], bgO[4];     // B fragment sets, even/odd tile parity

#define LDA_MG(DST, bufc, mg)                                                \
  do {                                                                       \
    _Pragma("unroll") for (int m_ = 0; m_ < 4; ++m_)                         \
      DST[m_] = *(const bf16x8*)(Abase + (bufc) * 16384 + (mg) * 4096 +      \
                                 m_ * 1024);                                 \
  } while (0)

#define LDB4(DST, bufc)                                                      \
  do {                                                                       \
    _Pragma("unroll") for (int n_ = 0; n_ < 4; ++n_)                         \
      DST[n_] = *(const bf16x8*)(Bbase + (bufc) * 16384 + n_ * 1024);        \
  } while (0)

#define MM16(AF, BG, mg)                                                     \
  do {                                                                       \
    _Pragma("unroll") for (int m_ = 0; m_ < 4; ++m_)                         \
      _Pragma("unroll") for (int n_ = 0; n_ < 4; ++n_)                       \
        acc[(mg) * 4 + m_][n_] = __builtin_amdgcn_mfma_f32_16x16x32_bf16(    \
            AF[m_], BG[n_], acc[(mg) * 4 + m_][n_], 0, 0, 0);                \
  } while (0)

  // one K-tile: 2 phases (see header)
#define TILE(T_, bufc, bgCur, bgNext, bufNext)                               \
  do {                                                                       \
    if ((T_) + 3 < NT) STG_ALL((T_) + 3);                                    \
    LDA_MG(afB, bufc, 1);                                                    \
    PRIO1(); MM16(afA, bgCur, 0); PRIO0();                                   \
    SB();                                                                    \
    if ((T_) + 1 < NT) { LDA_MG(afA, bufNext, 0); LDB4(bgNext, bufNext); }   \
    PRIO1(); MM16(afB, bgCur, 1); PRIO0();                                   \
    if ((T_) + 3 < NT) { WVM(4); } else { WVM(0); }                          \
    SB();                                                                    \
  } while (0)

  const int NT = K >> 5;   // K%128==0 => NT%4==0

  // prologue: stage tiles 0,1,2; drain to tile2-only in flight; preload T0
  STG_ALL(0); STG_ALL(1); STG_ALL(2);
  WVM(4); SB();
  LDA_MG(afA, 0, 0); LDB4(bgE, 0);

  for (int T = 0; T < NT; T += 4) {
    TILE(T,     0, bgE, bgO, 1);
    TILE(T + 1, 1, bgO, bgE, 2);
    TILE(T + 2, 2, bgE, bgO, 3);
    TILE(T + 3, 3, bgO, bgE, 0);
  }

  const float bias = bias_p[0];
#pragma unroll
  for (int m = 0; m < 8; ++m) {
#pragma unroll
    for (int n = 0; n < 4; ++n) {
      const int r = row0 + wm * 128 + m * 16 + fq * 4;
      const int c = col0 + wn * 64 + n * 16 + fr;
#pragma unroll
      for (int j = 0; j < 4; ++j)
        C[(size_t)(r + j) * N + c] = acc[m][n][j] + bias;
    }
  }
#undef STG_ALL
#undef LDA_MG
#undef LDB4
#undef MM16
#undef TILE
}

// ---------------------------------------------------------------------------
// m97-structure 128x128 GEMM (small XW = X*W^T, bf16 out)
// ---------------------------------------------------------------------------
__global__ void gemm_bt(const bf16* __restrict__ A, const bf16* __restrict__ B,
                        bf16* __restrict__ Cb, int M, int N, int K) {
  __shared__ bf16 As[128 * 32];
  __shared__ bf16 Bs[128 * 32];
  const int tid  = threadIdx.x;
  const int lane = tid & 63;
  const int wave = tid >> 6;
  const int wr = wave >> 1, wc = wave & 1;
  const int fr = lane & 15, fq = lane >> 4;
  const int row0 = blockIdx.y * 128, col0 = blockIdx.x * 128;

  f32x4 acc[4][4] = {};
  const int c0 = tid, c1 = 256 + tid;
  const bf16* Ag0 = A + (size_t)(row0 + (c0 >> 2)) * K + (c0 & 3) * 8;
  const bf16* Ag1 = A + (size_t)(row0 + (c1 >> 2)) * K + (c1 & 3) * 8;
  const bf16* Bg0 = B + (size_t)(col0 + (c0 >> 2)) * K + (c0 & 3) * 8;
  const bf16* Bg1 = B + (size_t)(col0 + (c1 >> 2)) * K + (c1 & 3) * 8;
  bf16* Al0 = As + (wave * 64) * 8;
  bf16* Al1 = As + (256 + wave * 64) * 8;
  bf16* Bl0 = Bs + (wave * 64) * 8;
  bf16* Bl1 = Bs + (256 + wave * 64) * 8;

  for (int k0 = 0; k0 < K; k0 += 32) {
    GLD_LDS(Ag0 + k0, Al0);
    GLD_LDS(Ag1 + k0, Al1);
    GLD_LDS(Bg0 + k0, Bl0);
    GLD_LDS(Bg1 + k0, Bl1);
    __syncthreads();
    bf16x8 af[4], bgf[4];
#pragma unroll
    for (int m = 0; m < 4; ++m)
      af[m] = *(const bf16x8*)&As[(wr * 64 + m * 16 + fr) * 32 + fq * 8];
#pragma unroll
    for (int n = 0; n < 4; ++n)
      bgf[n] = *(const bf16x8*)&Bs[(wc * 64 + n * 16 + fr) * 32 + fq * 8];
#pragma unroll
    for (int m = 0; m < 4; ++m)
#pragma unroll
      for (int n = 0; n < 4; ++n)
        acc[m][n] = __builtin_amdgcn_mfma_f32_16x16x32_bf16(af[m], bgf[n],
                                                            acc[m][n], 0, 0, 0);
    __syncthreads();
  }
#pragma unroll
  for (int m = 0; m < 4; ++m)
#pragma unroll
    for (int n = 0; n < 4; ++n) {
      const int r  = row0 + wr * 64 + m * 16 + fq * 4;
      const int cc = col0 + wc * 64 + n * 16 + fr;
#pragma unroll
      for (int j = 0; j < 4; ++j)
        Cb[(size_t)(r + j) * N + cc] = (bf16)acc[m][n][j];
    }
}

__global__ void cvt_f32_bf16(const float* __restrict__ in, bf16* __restrict__ out,
                             int n4) {
  int i = blockIdx.x * blockDim.x + threadIdx.x;
  if (i >= n4) return;
  const float4 v = ((const float4*)in)[i];
  bf16x4 o;
  o[0] = (bf16)v.x; o[1] = (bf16)v.y; o[2] = (bf16)v.z; o[3] = (bf16)v.w;
  ((bf16x4*)out)[i] = o;
}

__global__ void transpose_cvt_w(const float* __restrict__ W, bf16* __restrict__ Wt) {
  __shared__ float s[32][33];
  const int tx = threadIdx.x & 31;
  const int ty = threadIdx.x >> 5;
  const int n0 = blockIdx.x * 32;
  const int k0 = blockIdx.y * 32;
#pragma unroll
  for (int p = 0; p < 4; ++p)
    s[ty + p * 8][tx] = W[(size_t)(k0 + ty + p * 8) * 1024 + n0 + tx];
  __syncthreads();
#pragma unroll
  for (int p = 0; p < 4; ++p)
    Wt[(size_t)(n0 + ty + p * 8) * 1024 + k0 + tx] = (bf16)s[tx][ty + p * 8];
}

extern "C" void kernel_launch(void* const* d_in, const int* in_sizes, int n_in,
                              void* d_out, int out_size, void* d_ws, size_t ws_size,
                              hipStream_t stream) {
  const float* X = (const float*)d_in[0];   // (8192, 1024)
  const float* W = (const float*)d_in[1];   // (1024, 1024)
  const float* b = (const float*)d_in[2];   // (1,)
  float* out = (float*)d_out;               // (8192, 8192)

  const int Nn = 8192, D = 1024;
  char* ws = (char*)d_ws;
  bf16* Xb  = (bf16*)(ws);
  bf16* XWb = (bf16*)(ws + (size_t)16 * 1024 * 1024);
  bf16* Wt  = (bf16*)(ws + (size_t)32 * 1024 * 1024);

  cvt_f32_bf16<<<(Nn * D / 4 + 255) / 256, 256, 0, stream>>>(X, Xb, Nn * D / 4);
  transpose_cvt_w<<<dim3(D / 32, D / 32), 256, 0, stream>>>(W, Wt);
  gemm_bt<<<dim3(D / 128, Nn / 128), 256, 0, stream>>>(Xb, Wt, XWb, Nn, D, D);
  gemm256<<<(Nn / 256) * (Nn / 256), 512, 131072, stream>>>(XWb, Xb, out, b,
                                                            Nn, Nn, D);
}